// Round 3
// baseline (437.815 us; speedup 1.0000x reference)
//
#include <hip/hip_runtime.h>

// LIF recurrence: V = V + alpha*(I - V); spike = V>=1.0; V=0 on spike.
// N=65536 neurons (parallel), T=1024 steps (sequential per neuron).
// Bus floor: 256 MB read + 256 MB write ~= 82 us at 6.5 TB/s achieved.
//
// R4 == R3 resubmitted verbatim (R3 bench died on container acquisition,
// no data). Discriminating experiment: R1=425.7, R2=435.9 despite a major
// structural change -> dur_us appears pinned by harness poison fills
// (2x 1GiB fillBufferAligned @ ~164us each inside the timed graph; our
// kernel never ranks in rocprof top-5 => <163us on-chip). This version
// removes the last two structural candidates:
//  - single-phase interleave (no R2 phase-transition bubble; read+write
//    streams overlap on the bus for the whole kernel)
//  - stores deferred ONE CHUNK via bit-packed register: the 16 NT stores
//    per chunk read only a finalized scalar (prevw), are issued AFTER the
//    prefetch loads (so compute's load-wait is vmcnt(32), encodable, and
//    never chains behind younger stores), and sit entirely OFF the
//    V-recurrence dependency chain.
// If dur_us stays 425+-12, the harness-floor theory is confirmed.

#define T_STEPS 1024
#define NUM_NEURONS 65536
#define N NUM_NEURONS
#define BLOCK 256
#define U 16                       // steps per chunk == bits per packed word
#define NCHUNK (T_STEPS / U)       // 64 chunks

__global__ __launch_bounds__(BLOCK) void lif_kernel(const float* __restrict__ in,
                                                    float* __restrict__ out) {
    const int gid = blockIdx.x * BLOCK + threadIdx.x;   // [0, 65536)
    constexpr float alpha = 0.05f;                      // DT/TAU = 1/20
    constexpr float vth = 1.0f;

    const float* __restrict__ p = in + gid;
    float* __restrict__ q = out + gid;

    float V = 0.0f;                                     // V_RESET = 0
    float I[U], J[U];
    unsigned int prevw = 0u;

    // prologue: load chunk 0
#pragma unroll
    for (int u = 0; u < U; ++u) I[u] = p[(size_t)u * N];

    // first iteration (no deferred store yet): prefetch 1, compute 0
    {
#pragma unroll
        for (int u = 0; u < U; ++u) J[u] = p[(size_t)(U + u) * N];
        unsigned int w = 0u;
#pragma unroll
        for (int u = 0; u < U; ++u) {
            V = V + alpha * (I[u] - V);                 // reference order
            const bool s = (V >= vth);
            w |= s ? (1u << u) : 0u;
            V = s ? 0.0f : V;
        }
        prevw = w;
#pragma unroll
        for (int u = 0; u < U; ++u) I[u] = J[u];
    }

    // steady state: k = 1 .. NCHUNK-2
    for (int k = 1; k < NCHUNK - 1; ++k) {
        // 1) issue prefetch for chunk k+1 (oldest vmem ops this iter)
#pragma unroll
        for (int u = 0; u < U; ++u) J[u] = p[(size_t)((k + 1) * U + u) * N];
        // 2) drain chunk k-1 spikes (register-only source, no waits,
        //    younger than the loads so load-waits never cover them)
#pragma unroll
        for (int u = 0; u < U; ++u) {
            const float s = (prevw & (1u << u)) ? 1.0f : 0.0f;
            __builtin_nontemporal_store(s, q + (size_t)((k - 1) * U + u) * N);
        }
        // 3) compute chunk k (waits only on I[], issued last iteration)
        unsigned int w = 0u;
#pragma unroll
        for (int u = 0; u < U; ++u) {
            V = V + alpha * (I[u] - V);
            const bool s = (V >= vth);
            w |= s ? (1u << u) : 0u;
            V = s ? 0.0f : V;
        }
        prevw = w;
#pragma unroll
        for (int u = 0; u < U; ++u) I[u] = J[u];
    }

    // epilogue: store chunk NCHUNK-2, compute+store chunk NCHUNK-1
#pragma unroll
    for (int u = 0; u < U; ++u) {
        const float s = (prevw & (1u << u)) ? 1.0f : 0.0f;
        __builtin_nontemporal_store(s, q + (size_t)((NCHUNK - 2) * U + u) * N);
    }
    {
        unsigned int w = 0u;
#pragma unroll
        for (int u = 0; u < U; ++u) {
            V = V + alpha * (I[u] - V);
            const bool s = (V >= vth);
            w |= s ? (1u << u) : 0u;
            V = s ? 0.0f : V;
        }
#pragma unroll
        for (int u = 0; u < U; ++u) {
            const float s = (w & (1u << u)) ? 1.0f : 0.0f;
            __builtin_nontemporal_store(s, q + (size_t)((NCHUNK - 1) * U + u) * N);
        }
    }
}

extern "C" void kernel_launch(void* const* d_in, const int* in_sizes, int n_in,
                              void* d_out, int out_size, void* d_ws, size_t ws_size,
                              hipStream_t stream) {
    const float* in = (const float*)d_in[0];
    float* out = (float*)d_out;
    lif_kernel<<<NUM_NEURONS / BLOCK, BLOCK, 0, stream>>>(in, out);
}